// Round 12
// baseline (296.094 us; speedup 1.0000x reference)
//
#include <hip/hip_runtime.h>
#include <stdint.h>

// Problem constants
#define B_SZ   4
#define T_SEQ  2048
#define C_DIM  1024
#define N_HEAD 16
#define HEAD_D 64
#define QSCALE 0.18033688011112042f  // (1/sqrt(64)) * log2(e): exp2-domain attn

typedef unsigned short u16;
typedef unsigned int   u32;
typedef __bf16  bfv8  __attribute__((ext_vector_type(8)));
typedef float   f32x4 __attribute__((ext_vector_type(4)));

__device__ __forceinline__ u16 f2bf_hu(float f) {  // round-half-up, 1-ulp
  union { float f; u32 i; } u; u.f = f;
  return (u16)((u.i + 0x8000u) >> 16);
}
// half-up pack of two f32->bf16 into one u32.  BIT-EXACT reformulation of
// ((a+0x8000)>>16)|((b+0x8000)&0xFFFF0000) as 2 v_add + 1 v_perm_b32
// (selector 0x07060302: dst = {pb.b3,pb.b2,pa.b3,pa.b2}).  3 VALU vs 5.
// (R6 lesson: v_cvt_pk_bf16_f32 inline asm FAILED numerics on gfx950 --
// absmax 0.108 vs 0.068 threshold.  Do not use cvt_pk here.)
__device__ __forceinline__ u32 pkbf16(float a, float b) {
  union { float f; u32 i; } ua, ub; ua.f = a; ub.f = b;
  return __builtin_amdgcn_perm(ub.i + 0x8000u, ua.i + 0x8000u, 0x07060302u);
}
__device__ __forceinline__ float fexp2(float x) {
#if __has_builtin(__builtin_amdgcn_exp2f)
  return __builtin_amdgcn_exp2f(x);
#else
  return __expf(x * 0.69314718f);
#endif
}

// async global->LDS, 16B per lane. LDS dest is wave-uniform base + lane*16,
// so the per-lane lds pointer MUST equal base + lane*16 (linear layout).
__device__ __forceinline__ void async_cp16(const u16* __restrict__ g, u16* l) {
  __builtin_amdgcn_global_load_lds(
      (const __attribute__((address_space(1))) void*)g,
      (__attribute__((address_space(3))) void*)l, 16, 0, 0);
}

// fp32 -> bf16, x and all 4 weights in ONE dispatch.
// blocks 0..8191 -> x (8.4M el); blocks 8192+w*1024.. -> weight w (1M el).
__global__ __launch_bounds__(256) void cvt_all_kernel(
    const float* __restrict__ x,  const float* __restrict__ W0,
    const float* __restrict__ W1, const float* __restrict__ W2,
    const float* __restrict__ W3, u16* __restrict__ dst) {
  int bid = blockIdx.x;
  const float* s; u16* d; int local;
  if (bid < 8192) {
    s = x; d = dst; local = bid;
  } else {
    int w = (bid - 8192) >> 10;
    local  = (bid - 8192) & 1023;
    s = (w == 0) ? W0 : (w == 1) ? W1 : (w == 2) ? W2 : W3;
    d = dst + (size_t)(B_SZ * T_SEQ * C_DIM) + (size_t)w * (C_DIM * C_DIM);
  }
  int i = local * 256 + threadIdx.x;
  float4 v = ((const float4*)s)[i];
  int2 o; o.x = (int)pkbf16(v.x, v.y); o.y = (int)pkbf16(v.z, v.w);
  ((int2*)d)[i] = o;
}

// ---------------------------------------------------------------------------
// NT GEMM core v2 (R11): A via LDS-DMA (3-buffer rotation), B DIRECT FROM
// L2 into registers (double-buffered named reg sets Be/Bo).
// Rationale (R10 analysis): the old both-operands-in-LDS core moved 48 KB
// of LDS traffic per block-K-step (16 write + 32 read w/ 2x wave read
// amplification) = 2.36 GB/kernel ~ 34-45 us at measured LDS BW -- the
// true qkv bound.  W is 2 MB, L2-resident, reused 64x across M-blocks:
// per-wave global fragment loads (4x dwordx4/step; 16-lane groups share a
// 64B line) halve LDS traffic and run on the L2 port in parallel.
// Wait discipline: per step issue B(i+1)[4 loads] then A-DMA(i+2)[2];
// `s_waitcnt vmcnt(2)` + raw barrier drains A(i+1)+B(i+1), leaves A(i+2)
// in flight across the barrier.  B-reg correctness is additionally
// compiler-enforced (register dependence); the manual count covers the
// result-less DMA.  A buffer staged at step i was last ds_read at step
// i-2 (two barriers ago).  32 K-steps = prologue + 5 x 6-step unroll
// (lcm of 3 buffers x 2 reg sets) + 2-step tail.
// ---------------------------------------------------------------------------
__device__ __forceinline__ void mfma_stepB(const u16* As, int wm, int frow,
                                           int fk, bfv8 b0, bfv8 b1, bfv8 b2,
                                           bfv8 b3, f32x4 acc[4][4]) {
  bfv8 af[4];
#pragma unroll
  for (int mt = 0; mt < 4; mt++)
    af[mt] = *(const bfv8*)(As + (wm * 64 + mt * 16 + frow) * 32 + fk);
  __builtin_amdgcn_s_setprio(1);
#pragma unroll
  for (int mt = 0; mt < 4; mt++) {
    acc[mt][0] = __builtin_amdgcn_mfma_f32_16x16x32_bf16(af[mt], b0, acc[mt][0], 0, 0, 0);
    acc[mt][1] = __builtin_amdgcn_mfma_f32_16x16x32_bf16(af[mt], b1, acc[mt][1], 0, 0, 0);
    acc[mt][2] = __builtin_amdgcn_mfma_f32_16x16x32_bf16(af[mt], b2, acc[mt][2], 0, 0, 0);
    acc[mt][3] = __builtin_amdgcn_mfma_f32_16x16x32_bf16(af[mt], b3, acc[mt][3], 0, 0, 0);
  }
  __builtin_amdgcn_s_setprio(0);
}

__device__ __forceinline__ void gemm_core(const u16* __restrict__ A,
                                          const u16* __restrict__ Bw,
                                          int m0, int n0,
                                          f32x4 acc[4][4],
                                          u16* smem) {
  const int tid  = threadIdx.x;
  const int wave = tid >> 6;
  const int lane = tid & 63;
  const int frow = lane & 15;
  const int fk   = (lane >> 4) * 8;
  const int wm   = wave >> 1, wn = wave & 1;

  // A staging: thread t covers LDS bytes [t*16, t*16+16) of each 4KB half
  const int lrow = tid >> 2;        // 0..63
  const int lcol = (tid & 3) * 8;   // u16 col: 0/8/16/24
  const u16* ga0 = A + (size_t)(m0 + lrow)      * C_DIM + lcol;
  const u16* ga1 = A + (size_t)(m0 + 64 + lrow) * C_DIM + lcol;
  // B fragment source: row n0+wn*64+nt*16+frow, k-chunk fk; advances 32/step
  const u16* gB  = Bw + (size_t)(n0 + wn * 64 + frow) * C_DIM + fk;
  u16* b0 = smem;           // 3 x 8 KB A buffers (24 KB)
  u16* b1 = smem + 4096;
  u16* b2 = smem + 8192;
  const int so = tid * 8;   // u16 offset = byte offset tid*16
  bfv8 Be0, Be1, Be2, Be3, Bo0, Bo1, Bo2, Bo3;

#define STAGE_A(dst) do {                         \
    async_cp16(ga0, (dst) + so);                  \
    async_cp16(ga1, (dst) + 2048 + so);           \
    ga0 += 32; ga1 += 32;                         \
  } while (0)
#define LOAD_B(b) do {                            \
    b##0 = *(const bfv8*)(gB);                    \
    b##1 = *(const bfv8*)(gB + 16 * C_DIM);       \
    b##2 = *(const bfv8*)(gB + 32 * C_DIM);       \
    b##3 = *(const bfv8*)(gB + 48 * C_DIM);       \
    gB += 32;                                     \
  } while (0)
#define GSTEP(bufc, bufn2, B0_, B1_, B2_, B3_, BN) do {   \
    LOAD_B(BN);                                           \
    STAGE_A(bufn2);                                       \
    mfma_stepB(bufc, wm, frow, fk, B0_, B1_, B2_, B3_, acc); \
    asm volatile("s_waitcnt vmcnt(2)" ::: "memory");      \
    __builtin_amdgcn_s_barrier();                         \
  } while (0)

  STAGE_A(b0);   // A tile 0
  LOAD_B(Be);    // B tile 0
  STAGE_A(b1);   // A tile 1
  asm volatile("s_waitcnt vmcnt(2)" ::: "memory");  // tile0 A+B landed
  __builtin_amdgcn_s_barrier();

#pragma unroll 1
  for (int ii = 0; ii < 5; ii++) {         // steps 0..29
    GSTEP(b0, b2, Be0, Be1, Be2, Be3, Bo); // s%6==0: buf0, Be -> load Bo
    GSTEP(b1, b0, Bo0, Bo1, Bo2, Bo3, Be);
    GSTEP(b2, b1, Be0, Be1, Be2, Be3, Bo);
    GSTEP(b0, b2, Bo0, Bo1, Bo2, Bo3, Be);
    GSTEP(b1, b0, Be0, Be1, Be2, Be3, Bo);
    GSTEP(b2, b1, Bo0, Bo1, Bo2, Bo3, Be);
  }
  // step 30: compute b0/Be, load B(31); drain everything
  LOAD_B(Bo);
  mfma_stepB(b0, wm, frow, fk, Be0, Be1, Be2, Be3, acc);
  asm volatile("s_waitcnt vmcnt(0)" ::: "memory");
  __builtin_amdgcn_s_barrier();
  // step 31: compute b1/Bo
  mfma_stepB(b1, wm, frow, fk, Bo0, Bo1, Bo2, Bo3, acc);
#undef STAGE_A
#undef LOAD_B
#undef GSTEP
}

// QKV projections. Q (pre-scaled by QSCALE), K -> (B,H,T,D); V -> (B,H,D,T).
// Epilogues via wave-private LDS bounce -> contiguous 128B global stores.
__global__ __launch_bounds__(256) void gemm_qkv_kernel(
    const u16* __restrict__ X, const u16* __restrict__ Wq,
    const u16* __restrict__ Wk, const u16* __restrict__ Wv,
    u16* __restrict__ Qo, u16* __restrict__ Ko, u16* __restrict__ Vo) {
  __shared__ __align__(16) u16 smem[16384];  // 32 KB: 3x8KB A bufs, then bounce
  const u16* W = (blockIdx.z == 0) ? Wq : (blockIdx.z == 1) ? Wk : Wv;
  u16* dst     = (blockIdx.z == 0) ? Qo : (blockIdx.z == 1) ? Ko : Vo;
  const int m0 = blockIdx.x * 128, n0 = blockIdx.y * 128;

  f32x4 acc[4][4];
#pragma unroll
  for (int i = 0; i < 4; i++)
#pragma unroll
    for (int j = 0; j < 4; j++) acc[i][j] = {0.f, 0.f, 0.f, 0.f};

  gemm_core(X, W, m0, n0, acc, smem);
  __syncthreads();  // fragment reads done; smem reusable

  const int lane = threadIdx.x & 63, wave = threadIdx.x >> 6;
  const int wm = wave >> 1, wn = wave & 1;
  const int quad = lane >> 4, col = lane & 15;
  u16* buf = smem + wave * 4096;             // 8 KB wave-private
  const int bb = (m0 + wm * 64) >> 11;
  const int t0 = (m0 + wm * 64) & (T_SEQ - 1);
  const int h  = (n0 >> 6) + wn;

  if (blockIdx.z == 2) {
    // ---- V^T: buf[d 0..63][t granules of 4], int2-packed ----
#pragma unroll
    for (int mt = 0; mt < 4; mt++)
#pragma unroll
      for (int nt = 0; nt < 4; nt++) {
        int d_l = nt * 16 + col;
        int g   = mt * 4 + quad;
        int gp  = g ^ (d_l & 15);
        int2 o;
        o.x = (int)pkbf16(acc[mt][nt][0], acc[mt][nt][1]);
        o.y = (int)pkbf16(acc[mt][nt][2], acc[mt][nt][3]);
        *(int2*)(buf + d_l * 64 + gp * 4) = o;
      }
#pragma unroll
    for (int tt = 0; tt < 8; tt++) {
      int d_l = tt * 8 + (lane >> 3);
      int seg = lane & 7;
      int g0 = (2 * seg) ^ (d_l & 15), g1 = (2 * seg + 1) ^ (d_l & 15);
      int2 a  = *(const int2*)(buf + d_l * 64 + g0 * 4);
      int2 bv = *(const int2*)(buf + d_l * 64 + g1 * 4);
      int4 o; o.x = a.x; o.y = a.y; o.z = bv.x; o.w = bv.y;
      *(int4*)(Vo + (((size_t)(bb * N_HEAD + h) * HEAD_D + d_l) * T_SEQ
                     + t0 + seg * 8)) = o;
    }
  } else {
    // ---- Q/K: buf[m 0..63][n 0..63], scalar writes + 8-granule swizzle ----
    const float sc = (blockIdx.z == 0) ? QSCALE : 1.0f;
#pragma unroll
    for (int mt = 0; mt < 4; mt++)
#pragma unroll
      for (int nt = 0; nt < 4; nt++)
#pragma unroll
        for (int r = 0; r < 4; r++) {
          int m_l = mt * 16 + quad * 4 + r;
          int n_l = nt * 16 + col;
          int gp = (n_l >> 3) ^ (m_l & 7);
          buf[m_l * 64 + gp * 8 + (n_l & 7)] = f2bf_hu(acc[mt][nt][r] * sc);
        }
#pragma unroll
    for (int tt = 0; tt < 8; tt++) {
      int m_l = tt * 8 + (lane >> 3);
      int seg = lane & 7;
      int gp = seg ^ (m_l & 7);
      int4 o = *(const int4*)(buf + m_l * 64 + gp * 8);
      *(int4*)(dst + (((size_t)(bb * N_HEAD + h) * T_SEQ + t0 + m_l) * HEAD_D
                      + seg * 8)) = o;
    }
  }
}

// Output projection: (B,T,C) fp32, epilogue via wave-private f32 bounce.
__global__ __launch_bounds__(256) void gemm_out_kernel(
    const u16* __restrict__ Y, const u16* __restrict__ Wo,
    float* __restrict__ Out) {
  __shared__ __align__(16) u16 smem[16384];  // 32 KB
  const int m0 = blockIdx.x * 128, n0 = blockIdx.y * 128;

  f32x4 acc[4][4];
#pragma unroll
  for (int i = 0; i < 4; i++)
#pragma unroll
    for (int j = 0; j < 4; j++) acc[i][j] = {0.f, 0.f, 0.f, 0.f};

  gemm_core(Y, Wo, m0, n0, acc, smem);
  __syncthreads();

  const int lane = threadIdx.x & 63, wave = threadIdx.x >> 6;
  const int wm = wave >> 1, wn = wave & 1;
  const int quad = lane >> 4, col = lane & 15;
  float* bufF = (float*)(smem + wave * 4096);  // 2048 floats wave-private

#pragma unroll
  for (int c = 0; c < 2; c++) {
#pragma unroll
    for (int mt = 0; mt < 4; mt++)
#pragma unroll
      for (int nn = 0; nn < 2; nn++)
#pragma unroll
        for (int r = 0; r < 4; r++) {
          int nt = 2 * c + nn;
          int m_l = mt * 16 + quad * 4 + r;
          int n_l = nn * 16 + col;
          int gp = (n_l >> 2) ^ (m_l & 7);
          bufF[m_l * 32 + gp * 4 + (n_l & 3)] = acc[mt][nt][r];
        }
#pragma unroll
    for (int tt = 0; tt < 8; tt++) {
      int m_l = tt * 8 + (lane >> 3);
      int seg = lane & 7;
      int gp = seg ^ (m_l & 7);
      float4 o = *(const float4*)(bufF + m_l * 32 + gp * 4);
      *(float4*)(Out + (size_t)(m0 + wm * 64 + m_l) * C_DIM
                 + n0 + wn * 64 + c * 32 + seg * 4) = o;
    }
  }
}

// ---------------------------------------------------------------------------
// MFMA flash attention (causal), exp2 domain, fixed-max softmax without
// the max subtraction (p = exp2(s); 2^-M row scale cancels in O/l).
// Block = (b,h) x 128-q tile; 4 waves x 32 q; 64-key tiles.
// K/V staged via global_load_lds DMA, double-buffered, ONE barrier per
// k-tile; XOR granule swizzle applied on the GLOBAL SOURCE address (LDS
// dest linear, rule #21) -- bit-identical content to the pre-R10 layout.
// LDS 48 KB -> 3 blocks/CU.  (Measured R10: passed, total -2.3us.)
// ---------------------------------------------------------------------------
#define ATT_Q 128

__global__ __launch_bounds__(256, 3) void attn_kernel(
    const u16* __restrict__ Qg, const u16* __restrict__ Kg,
    const u16* __restrict__ Vtg, u16* __restrict__ Yg) {
  __shared__ __align__(16) u16 QPs[128 * 64];   // Q staging, P bounce, Y bounce
  __shared__ __align__(16) u16 Ks[2 * 64 * 64]; // K double buffer (2 x 8 KB)
  __shared__ __align__(16) u16 Vt[2 * 64 * 64]; // V^T double buffer

  const int tid = threadIdx.x;
  const int wave = tid >> 6, lane = tid & 63;
  const int quad = lane >> 4, l15 = lane & 15;
  const int bh = blockIdx.x;
  const int b = bh >> 4, h = bh & 15;
  const int yy = blockIdx.y, gq = yy >> 2, rq = yy & 3;
  const int qt = (gq == 0) ? 15 - rq : (gq == 1) ? rq
               : (gq == 2) ? 11 - rq : 4 + rq;
  const int q0 = qt * ATT_Q;

  // ---- DMA staging map: thread covers LDS bytes [tid*16] and [4KB+tid*16]
  // of each 8KB tile.  row = tid>>3 (and +32), granule g = tid&7; source
  // granule is pre-swizzled: g ^ (row&7)  (row and row+32 share row&7).
  const u16* Kbase = Kg  + (size_t)bh * T_SEQ * HEAD_D;
  const u16* Vbase = Vtg + (size_t)bh * HEAD_D * T_SEQ;
  const int trow = tid >> 3;             // 0..31
  const int gx   = (tid & 7) ^ (trow & 7);

#define STAGE_KV(slot, kt_) do {                                          \
    const u16* ks0 = Kbase + (size_t)(((kt_) << 6) + trow) * HEAD_D + gx * 8; \
    const u16* vs0 = Vbase + (size_t)trow * T_SEQ + ((kt_) << 6) + gx * 8;    \
    u16* kd = Ks + (slot) * 4096 + tid * 8;                               \
    u16* vd = Vt + (slot) * 4096 + tid * 8;                               \
    async_cp16(ks0, kd);                                                  \
    async_cp16(ks0 + 32 * HEAD_D, kd + 2048);                             \
    async_cp16(vs0, vd);                                                  \
    async_cp16(vs0 + (size_t)32 * T_SEQ, vd + 2048);                      \
  } while (0)

  STAGE_KV(0, 0);  // tile 0 DMA overlaps Q staging below

  // ---- stage Q tile (already exp2-prescaled by projection) ----
  {
    const int row = tid >> 1;
    const int c0 = (tid & 1) * 32;
    const u16* gp = Qg + ((size_t)bh * T_SEQ + q0 + row) * HEAD_D + c0;
#pragma unroll
    for (int g = 0; g < 4; g++) {
      int4 v = *(const int4*)(gp + g * 8);
      int pg = ((c0 >> 3) + g) ^ (row & 7);
      *(int4*)(QPs + row * 64 + pg * 8) = v;
    }
  }
  __syncthreads();  // drains vmcnt+lgkm: Q written, K/V tile 0 landed

  bfv8 qb[2][2];
#pragma unroll
  for (int nt = 0; nt < 2; nt++)
#pragma unroll
    for (int ks = 0; ks < 2; ks++) {
      int q = wave * 32 + nt * 16 + l15;
      int pg = (ks * 4 + quad) ^ (q & 7);
      qb[nt][ks] = *(const bfv8*)(QPs + q * 64 + pg * 8);
    }

  float l_i[2] = {0.f, 0.f};
  f32x4 ao[4][2];
#pragma unroll
  for (int mt = 0; mt < 4; mt++)
#pragma unroll
    for (int nt = 0; nt < 2; nt++) ao[mt][nt] = {0.f, 0.f, 0.f, 0.f};

  const int ktmax = 2 * qt + 1;
  for (int kt = 0; kt <= ktmax; kt++) {
    if (kt < ktmax) STAGE_KV((kt + 1) & 1, kt + 1);  // in flight under compute
    const u16* Ksb = Ks + (kt & 1) * 4096;
    const u16* Vtb = Vt + (kt & 1) * 4096;

    // ---- S^T = K · Q^T ----
    f32x4 as[4][2];
#pragma unroll
    for (int mt = 0; mt < 4; mt++)
#pragma unroll
      for (int nt = 0; nt < 2; nt++) as[mt][nt] = {0.f, 0.f, 0.f, 0.f};
#pragma unroll
    for (int mt = 0; mt < 4; mt++) {
      bfv8 ka[2];
#pragma unroll
      for (int ks = 0; ks < 2; ks++) {
        int key = mt * 16 + l15;
        int pg = (ks * 4 + quad) ^ (key & 7);
        ka[ks] = *(const bfv8*)(Ksb + key * 64 + pg * 8);
      }
#pragma unroll
      for (int nt = 0; nt < 2; nt++)
#pragma unroll
        for (int ks = 0; ks < 2; ks++)
          as[mt][nt] = __builtin_amdgcn_mfma_f32_16x16x32_bf16(
              ka[ks], qb[nt][ks], as[mt][nt], 0, 0, 0);
    }

    // ---- softmax: p = exp2(s) (fixed-max scale cancels in O/l) ----
    const bool diag = (kt >= 2 * qt);
#pragma unroll
    for (int nt = 0; nt < 2; nt++) {
      const int q_l = wave * 32 + nt * 16 + l15;
      const int q_g = q0 + q_l;
      float lacc = 0.f;
#pragma unroll
      for (int mt = 0; mt < 4; mt++) {
        float p[4];
#pragma unroll
        for (int r = 0; r < 4; r++) {
          float s = as[mt][nt][r];
          if (diag) {
            int key_g = kt * 64 + mt * 16 + quad * 4 + r;
            if (key_g > q_g) s = -1e30f;  // exp2 -> 0
          }
          p[r] = fexp2(s);
        }
        lacc += (p[0] + p[1]) + (p[2] + p[3]);
        int pg = (2 * mt + (quad >> 1)) ^ (q_l & 7);
        int2 o;
        o.x = (int)pkbf16(p[0], p[1]);
        o.y = (int)pkbf16(p[2], p[3]);
        *(int2*)(QPs + q_l * 64 + pg * 8 + (quad & 1) * 4) = o;
      }
      l_i[nt] += lacc;
    }

    // ---- O^T += V^T · P ----
    bfv8 pf[2][2];
#pragma unroll
    for (int nt = 0; nt < 2; nt++)
#pragma unroll
      for (int ks = 0; ks < 2; ks++) {
        int q_l = wave * 32 + nt * 16 + l15;
        int pg = (ks * 4 + quad) ^ (q_l & 7);
        pf[nt][ks] = *(const bfv8*)(QPs + q_l * 64 + pg * 8);
      }
#pragma unroll
    for (int mt = 0; mt < 4; mt++) {
      bfv8 va[2];
#pragma unroll
      for (int ks = 0; ks < 2; ks++) {
        int d = mt * 16 + l15;
        int pg = (ks * 4 + quad) ^ (d & 7);
        va[ks] = *(const bfv8*)(Vtb + d * 64 + pg * 8);
      }
#pragma unroll
      for (int nt = 0; nt < 2; nt++)
#pragma unroll
        for (int ks = 0; ks < 2; ks++)
          ao[mt][nt] = __builtin_amdgcn_mfma_f32_16x16x32_bf16(
              va[ks], pf[nt][ks], ao[mt][nt], 0, 0, 0);
    }

    // next tile landed; this tile's LDS reads all retired (consumed by
    // the MFMAs above).  One barrier per k-tile.
    asm volatile("s_waitcnt vmcnt(0)" ::: "memory");
    __builtin_amdgcn_s_barrier();
  }
#undef STAGE_KV

  // ---- final l reduction across quads ----
#pragma unroll
  for (int nt = 0; nt < 2; nt++) {
    l_i[nt] += __shfl_xor(l_i[nt], 16);
    l_i[nt] += __shfl_xor(l_i[nt], 32);
  }

  // ---- epilogue: O^T -> LDS bounce (QPs) -> coalesced Y stores ----
  __syncthreads();
#pragma unroll
  for (int nt = 0; nt < 2; nt++) {
    float inv = 1.0f / l_i[nt];
    int q_l = wave * 32 + nt * 16 + l15;
#pragma unroll
    for (int mt = 0; mt < 4; mt++) {
      int g = mt * 4 + quad;
      int gp = g ^ (q_l & 15);
      int2 o;
      o.x = (int)pkbf16(ao[mt][nt][0] * inv, ao[mt][nt][1] * inv);
      o.y = (int)pkbf16(ao[mt][nt][2] * inv, ao[mt][nt][3] * inv);
      *(int2*)(QPs + q_l * 64 + gp * 4) = o;
    }
  }
  __syncthreads();
#pragma unroll
  for (int rr = 0; rr < 4; rr++) {
    int q   = rr * 32 + (tid >> 3);
    int seg = tid & 7;
    int g0 = (2 * seg) ^ (q & 15), g1 = (2 * seg + 1) ^ (q & 15);
    int2 a  = *(const int2*)(QPs + q * 64 + g0 * 4);
    int2 bv = *(const int2*)(QPs + q * 64 + g1 * 4);
    int4 o; o.x = a.x; o.y = a.y; o.z = bv.x; o.w = bv.y;
    *(int4*)(Yg + ((size_t)b * T_SEQ + q0 + q) * C_DIM + h * HEAD_D + seg * 8) = o;
  }
}

extern "C" void kernel_launch(void* const* d_in, const int* in_sizes, int n_in,
                              void* d_out, int out_size, void* d_ws, size_t ws_size,
                              hipStream_t stream) {
  const float* x  = (const float*)d_in[0];
  const float* Wq = (const float*)d_in[1];
  const float* Wk = (const float*)d_in[2];
  const float* Wv = (const float*)d_in[3];
  const float* Wo = (const float*)d_in[4];
  float* out = (float*)d_out;

  const size_t NE = (size_t)B_SZ * T_SEQ * C_DIM;  // 8388608
  const size_t NW = (size_t)C_DIM * C_DIM;         // 1048576
  u16* xbf = (u16*)d_ws;
  u16* wqb = xbf + NE;   // 4 weight buffers contiguous
  u16* wkb = wqb + NW;
  u16* wvb = wkb + NW;
  u16* wob = wvb + NW;
  u16* qws = wob + NW;
  u16* kws = qws + NE;
  u16* vws = kws + NE;   // V^T layout (B,H,D,T)
  u16* yws = vws + NE;

  // x: 8192 blocks; weights: 4 x 1024 blocks — one dispatch
  cvt_all_kernel<<<8192 + 4096, 256, 0, stream>>>(x, Wq, Wk, Wv, Wo, xbf);

  dim3 g1(T_SEQ * B_SZ / 128, C_DIM / 128, 3);
  gemm_qkv_kernel<<<g1, 256, 0, stream>>>(xbf, wqb, wkb, wvb, qws, kws, vws);

  dim3 g2(B_SZ * N_HEAD, T_SEQ / ATT_Q);
  attn_kernel<<<g2, 256, 0, stream>>>(qws, kws, vws, yws);

  dim3 g3(T_SEQ * B_SZ / 128, C_DIM / 128);
  gemm_out_kernel<<<g3, 256, 0, stream>>>(yws, wob, out);
}

// Round 13
// 234.773 us; speedup vs baseline: 1.2612x; 1.2612x over previous
//
#include <hip/hip_runtime.h>
#include <stdint.h>

// Problem constants
#define B_SZ   4
#define T_SEQ  2048
#define C_DIM  1024
#define N_HEAD 16
#define HEAD_D 64
#define QSCALE 0.18033688011112042f  // (1/sqrt(64)) * log2(e): exp2-domain attn

typedef unsigned short u16;
typedef unsigned int   u32;
typedef __bf16  bfv8  __attribute__((ext_vector_type(8)));
typedef float   f32x4 __attribute__((ext_vector_type(4)));

__device__ __forceinline__ u16 f2bf_hu(float f) {  // round-half-up, 1-ulp
  union { float f; u32 i; } u; u.f = f;
  return (u16)((u.i + 0x8000u) >> 16);
}
// half-up pack of two f32->bf16 into one u32.  BIT-EXACT reformulation of
// ((a+0x8000)>>16)|((b+0x8000)&0xFFFF0000) as 2 v_add + 1 v_perm_b32
// (selector 0x07060302: dst = {pb.b3,pb.b2,pa.b3,pa.b2}).  3 VALU vs 5.
// (R6 lesson: v_cvt_pk_bf16_f32 inline asm FAILED numerics on gfx950 --
// absmax 0.108 vs 0.068 threshold.  Do not use cvt_pk here.)
__device__ __forceinline__ u32 pkbf16(float a, float b) {
  union { float f; u32 i; } ua, ub; ua.f = a; ub.f = b;
  return __builtin_amdgcn_perm(ub.i + 0x8000u, ua.i + 0x8000u, 0x07060302u);
}
__device__ __forceinline__ float fexp2(float x) {
#if __has_builtin(__builtin_amdgcn_exp2f)
  return __builtin_amdgcn_exp2f(x);
#else
  return __expf(x * 0.69314718f);
#endif
}

// async global->LDS, 16B per lane. LDS dest is wave-uniform base + lane*16,
// so the per-lane lds pointer MUST equal base + lane*16 (linear layout).
__device__ __forceinline__ void async_cp16(const u16* __restrict__ g, u16* l) {
  __builtin_amdgcn_global_load_lds(
      (const __attribute__((address_space(1))) void*)g,
      (__attribute__((address_space(3))) void*)l, 16, 0, 0);
}

// fp32 -> bf16, x and all 4 weights in ONE dispatch.
// blocks 0..8191 -> x (8.4M el); blocks 8192+w*1024.. -> weight w (1M el).
__global__ __launch_bounds__(256) void cvt_all_kernel(
    const float* __restrict__ x,  const float* __restrict__ W0,
    const float* __restrict__ W1, const float* __restrict__ W2,
    const float* __restrict__ W3, u16* __restrict__ dst) {
  int bid = blockIdx.x;
  const float* s; u16* d; int local;
  if (bid < 8192) {
    s = x; d = dst; local = bid;
  } else {
    int w = (bid - 8192) >> 10;
    local  = (bid - 8192) & 1023;
    s = (w == 0) ? W0 : (w == 1) ? W1 : (w == 2) ? W2 : W3;
    d = dst + (size_t)(B_SZ * T_SEQ * C_DIM) + (size_t)w * (C_DIM * C_DIM);
  }
  int i = local * 256 + threadIdx.x;
  float4 v = ((const float4*)s)[i];
  int2 o; o.x = (int)pkbf16(v.x, v.y); o.y = (int)pkbf16(v.z, v.w);
  ((int2*)d)[i] = o;
}

// ---------------------------------------------------------------------------
// NT GEMM core, 3-buffer deep pipeline with COUNTED vmcnt (T3+T4):
// C[m,n] = sum_k A[m,k]*Bw[n,k]; 128x128 tile, BK=32, 4 waves 2x2,
// 4x4 of 16x16x32 MFMA.  3 buffers (48 KB), counted vmcnt(4) + raw
// barrier per step; prefetch loads stay in flight across barriers.
// MEASURED BEST: qkv 69.7/69.8/70.1us across three sessions (R9-R11).
// R11 ERRATA: B-direct-from-L2 regressed to 115us (scattered 16B L2
// loads, 64 lines/wave-load, latency-bound: MfmaUtil 17.5).  Both
// operands stay in LDS via DMA.  SQ_LDS_BANK_CONFLICT ~6.36M here is
// the global_load_lds DMA-write floor, not read conflicts (R5/R6).
// ---------------------------------------------------------------------------
__device__ __forceinline__ void mfma_step(const u16* Sbuf, int wm, int wn,
                                          int frow, int fk, f32x4 acc[4][4]) {
  const u16* As = Sbuf;           // 128x32 u16 (8 KB)
  const u16* Bs = Sbuf + 4096;    // 128x32 u16 (8 KB)
  bfv8 af[4], bfr[4];
#pragma unroll
  for (int mt = 0; mt < 4; mt++)
    af[mt] = *(const bfv8*)(As + (wm * 64 + mt * 16 + frow) * 32 + fk);
#pragma unroll
  for (int nt = 0; nt < 4; nt++)
    bfr[nt] = *(const bfv8*)(Bs + (wn * 64 + nt * 16 + frow) * 32 + fk);
  __builtin_amdgcn_s_setprio(1);
#pragma unroll
  for (int mt = 0; mt < 4; mt++)
#pragma unroll
    for (int nt = 0; nt < 4; nt++)
      acc[mt][nt] = __builtin_amdgcn_mfma_f32_16x16x32_bf16(
          af[mt], bfr[nt], acc[mt][nt], 0, 0, 0);
  __builtin_amdgcn_s_setprio(0);
}

__device__ __forceinline__ void gemm_core(const u16* __restrict__ A,
                                          const u16* __restrict__ Bw,
                                          int m0, int n0,
                                          f32x4 acc[4][4],
                                          u16* smem) {
  const int tid  = threadIdx.x;
  const int wave = tid >> 6;
  const int lane = tid & 63;
  const int frow = lane & 15;
  const int fk   = (lane >> 4) * 8;
  const int wm   = wave >> 1, wn = wave & 1;

  // staging map: thread t covers LDS bytes [t*16, t*16+16) of each 4KB chunk
  const int lrow = tid >> 2;        // 0..63 (row within chunk)
  const int lcol = (tid & 3) * 8;   // u16 col: 0/8/16/24
  const u16* ga0 = A  + (size_t)(m0 + lrow)      * C_DIM + lcol;
  const u16* ga1 = A  + (size_t)(m0 + 64 + lrow) * C_DIM + lcol;
  const u16* gb0 = Bw + (size_t)(n0 + lrow)      * C_DIM + lcol;
  const u16* gb1 = Bw + (size_t)(n0 + 64 + lrow) * C_DIM + lcol;
  u16* b0 = smem;           // 3 x 16 KB buffers
  u16* b1 = smem + 8192;
  u16* b2 = smem + 16384;
  const int so = tid * 8;   // byte offset tid*16 within each 4KB chunk

#define STAGE_TO(dst) do {                        \
    async_cp16(ga0, (dst) + so);                  \
    async_cp16(ga1, (dst) + 2048 + so);           \
    async_cp16(gb0, (dst) + 4096 + so);           \
    async_cp16(gb1, (dst) + 6144 + so);           \
    ga0 += 32; ga1 += 32; gb0 += 32; gb1 += 32;   \
  } while (0)
#define WAIT4_BAR do {                                      \
    asm volatile("s_waitcnt vmcnt(4)" ::: "memory");        \
    __builtin_amdgcn_s_barrier();                           \
  } while (0)

  STAGE_TO(b0);   // tile 0
  STAGE_TO(b1);   // tile 1  (8 loads outstanding)
  WAIT4_BAR;      // tile 0 landed (4 newer remain in flight)

  // steady state: 10 triples cover steps 0..29, staging tiles 2..31
#pragma unroll 1
  for (int ii = 0; ii < 30; ii += 3) {
    STAGE_TO(b2);                         // tile ii+2 (b2 held tile ii-1)
    mfma_step(b0, wm, wn, frow, fk, acc); // tile ii
    WAIT4_BAR;                            // tile ii+1 landed

    STAGE_TO(b0);                         // tile ii+3
    mfma_step(b1, wm, wn, frow, fk, acc); // tile ii+1
    WAIT4_BAR;                            // tile ii+2 landed

    STAGE_TO(b1);                         // tile ii+4
    mfma_step(b2, wm, wn, frow, fk, acc); // tile ii+2
    WAIT4_BAR;                            // tile ii+3 landed
  }
  // tail: tiles 30 (in b0, landed) and 31 (in b1, 4 loads outstanding)
  mfma_step(b0, wm, wn, frow, fk, acc);   // tile 30
  asm volatile("s_waitcnt vmcnt(0)" ::: "memory");
  __builtin_amdgcn_s_barrier();           // tile 31 landed, all waves
  mfma_step(b1, wm, wn, frow, fk, acc);   // tile 31
#undef STAGE_TO
#undef WAIT4_BAR
}

// QKV projections. Q (pre-scaled by QSCALE), K -> (B,H,T,D); V -> (B,H,D,T).
// Epilogues via wave-private LDS bounce -> contiguous 128B global stores.
__global__ __launch_bounds__(256) void gemm_qkv_kernel(
    const u16* __restrict__ X, const u16* __restrict__ Wq,
    const u16* __restrict__ Wk, const u16* __restrict__ Wv,
    u16* __restrict__ Qo, u16* __restrict__ Ko, u16* __restrict__ Vo) {
  __shared__ __align__(16) u16 smem[24576];  // 48 KB: 3x(As|Bs), then bounce
  const u16* W = (blockIdx.z == 0) ? Wq : (blockIdx.z == 1) ? Wk : Wv;
  u16* dst     = (blockIdx.z == 0) ? Qo : (blockIdx.z == 1) ? Ko : Vo;
  const int m0 = blockIdx.x * 128, n0 = blockIdx.y * 128;

  f32x4 acc[4][4];
#pragma unroll
  for (int i = 0; i < 4; i++)
#pragma unroll
    for (int j = 0; j < 4; j++) acc[i][j] = {0.f, 0.f, 0.f, 0.f};

  gemm_core(X, W, m0, n0, acc, smem);
  __syncthreads();  // fragment reads done; smem reusable

  const int lane = threadIdx.x & 63, wave = threadIdx.x >> 6;
  const int wm = wave >> 1, wn = wave & 1;
  const int quad = lane >> 4, col = lane & 15;
  u16* buf = smem + wave * 4096;             // 8 KB wave-private
  const int bb = (m0 + wm * 64) >> 11;
  const int t0 = (m0 + wm * 64) & (T_SEQ - 1);
  const int h  = (n0 >> 6) + wn;

  if (blockIdx.z == 2) {
    // ---- V^T: buf[d 0..63][t granules of 4], int2-packed ----
#pragma unroll
    for (int mt = 0; mt < 4; mt++)
#pragma unroll
      for (int nt = 0; nt < 4; nt++) {
        int d_l = nt * 16 + col;
        int g   = mt * 4 + quad;
        int gp  = g ^ (d_l & 15);
        int2 o;
        o.x = (int)pkbf16(acc[mt][nt][0], acc[mt][nt][1]);
        o.y = (int)pkbf16(acc[mt][nt][2], acc[mt][nt][3]);
        *(int2*)(buf + d_l * 64 + gp * 4) = o;
      }
#pragma unroll
    for (int tt = 0; tt < 8; tt++) {
      int d_l = tt * 8 + (lane >> 3);
      int seg = lane & 7;
      int g0 = (2 * seg) ^ (d_l & 15), g1 = (2 * seg + 1) ^ (d_l & 15);
      int2 a  = *(const int2*)(buf + d_l * 64 + g0 * 4);
      int2 bv = *(const int2*)(buf + d_l * 64 + g1 * 4);
      int4 o; o.x = a.x; o.y = a.y; o.z = bv.x; o.w = bv.y;
      *(int4*)(Vo + (((size_t)(bb * N_HEAD + h) * HEAD_D + d_l) * T_SEQ
                     + t0 + seg * 8)) = o;
    }
  } else {
    // ---- Q/K: buf[m 0..63][n 0..63], scalar writes + 8-granule swizzle ----
    const float sc = (blockIdx.z == 0) ? QSCALE : 1.0f;
#pragma unroll
    for (int mt = 0; mt < 4; mt++)
#pragma unroll
      for (int nt = 0; nt < 4; nt++)
#pragma unroll
        for (int r = 0; r < 4; r++) {
          int m_l = mt * 16 + quad * 4 + r;
          int n_l = nt * 16 + col;
          int gp = (n_l >> 3) ^ (m_l & 7);
          buf[m_l * 64 + gp * 8 + (n_l & 7)] = f2bf_hu(acc[mt][nt][r] * sc);
        }
#pragma unroll
    for (int tt = 0; tt < 8; tt++) {
      int m_l = tt * 8 + (lane >> 3);
      int seg = lane & 7;
      int gp = seg ^ (m_l & 7);
      int4 o = *(const int4*)(buf + m_l * 64 + gp * 8);
      *(int4*)(dst + (((size_t)(bb * N_HEAD + h) * T_SEQ + t0 + m_l) * HEAD_D
                      + seg * 8)) = o;
    }
  }
}

// Output projection: (B,T,C) fp32, epilogue via wave-private f32 bounce.
__global__ __launch_bounds__(256) void gemm_out_kernel(
    const u16* __restrict__ Y, const u16* __restrict__ Wo,
    float* __restrict__ Out) {
  __shared__ __align__(16) u16 smem[24576];  // 48 KB
  const int m0 = blockIdx.x * 128, n0 = blockIdx.y * 128;

  f32x4 acc[4][4];
#pragma unroll
  for (int i = 0; i < 4; i++)
#pragma unroll
    for (int j = 0; j < 4; j++) acc[i][j] = {0.f, 0.f, 0.f, 0.f};

  gemm_core(Y, Wo, m0, n0, acc, smem);
  __syncthreads();

  const int lane = threadIdx.x & 63, wave = threadIdx.x >> 6;
  const int wm = wave >> 1, wn = wave & 1;
  const int quad = lane >> 4, col = lane & 15;
  float* bufF = (float*)(smem + wave * 4096);  // 2048 floats wave-private

#pragma unroll
  for (int c = 0; c < 2; c++) {
#pragma unroll
    for (int mt = 0; mt < 4; mt++)
#pragma unroll
      for (int nn = 0; nn < 2; nn++)
#pragma unroll
        for (int r = 0; r < 4; r++) {
          int nt = 2 * c + nn;
          int m_l = mt * 16 + quad * 4 + r;
          int n_l = nn * 16 + col;
          int gp = (n_l >> 2) ^ (m_l & 7);
          bufF[m_l * 32 + gp * 4 + (n_l & 3)] = acc[mt][nt][r];
        }
#pragma unroll
    for (int tt = 0; tt < 8; tt++) {
      int m_l = tt * 8 + (lane >> 3);
      int seg = lane & 7;
      int gp = seg ^ (m_l & 7);
      float4 o = *(const float4*)(bufF + m_l * 32 + gp * 4);
      *(float4*)(Out + (size_t)(m0 + wm * 64 + m_l) * C_DIM
                 + n0 + wn * 64 + c * 32 + seg * 4) = o;
    }
  }
}

// ---------------------------------------------------------------------------
// MFMA flash attention (causal), exp2 domain, fixed-max softmax without
// the max subtraction (p = exp2(s); 2^-M row scale cancels in O/l).
// Block = (b,h) x 128-q tile; 4 waves x 32 q; 64-key tiles.
// K/V staged via global_load_lds DMA, double-buffered, ONE barrier per
// k-tile; XOR granule swizzle applied on the GLOBAL SOURCE address (LDS
// dest linear, rule #21) -- bit-identical content to the pre-R10 layout.
// LDS 48 KB -> 3 blocks/CU.  (Measured R10: passed, total 236.3us.)
// ---------------------------------------------------------------------------
#define ATT_Q 128

__global__ __launch_bounds__(256, 3) void attn_kernel(
    const u16* __restrict__ Qg, const u16* __restrict__ Kg,
    const u16* __restrict__ Vtg, u16* __restrict__ Yg) {
  __shared__ __align__(16) u16 QPs[128 * 64];   // Q staging, P bounce, Y bounce
  __shared__ __align__(16) u16 Ks[2 * 64 * 64]; // K double buffer (2 x 8 KB)
  __shared__ __align__(16) u16 Vt[2 * 64 * 64]; // V^T double buffer

  const int tid = threadIdx.x;
  const int wave = tid >> 6, lane = tid & 63;
  const int quad = lane >> 4, l15 = lane & 15;
  const int bh = blockIdx.x;
  const int b = bh >> 4, h = bh & 15;
  const int yy = blockIdx.y, gq = yy >> 2, rq = yy & 3;
  const int qt = (gq == 0) ? 15 - rq : (gq == 1) ? rq
               : (gq == 2) ? 11 - rq : 4 + rq;
  const int q0 = qt * ATT_Q;

  // ---- DMA staging map: thread covers LDS bytes [tid*16] and [4KB+tid*16]
  // of each 8KB tile.  row = tid>>3 (and +32), granule g = tid&7; source
  // granule is pre-swizzled: g ^ (row&7)  (row and row+32 share row&7).
  const u16* Kbase = Kg  + (size_t)bh * T_SEQ * HEAD_D;
  const u16* Vbase = Vtg + (size_t)bh * HEAD_D * T_SEQ;
  const int trow = tid >> 3;             // 0..31
  const int gx   = (tid & 7) ^ (trow & 7);

#define STAGE_KV(slot, kt_) do {                                          \
    const u16* ks0 = Kbase + (size_t)(((kt_) << 6) + trow) * HEAD_D + gx * 8; \
    const u16* vs0 = Vbase + (size_t)trow * T_SEQ + ((kt_) << 6) + gx * 8;    \
    u16* kd = Ks + (slot) * 4096 + tid * 8;                               \
    u16* vd = Vt + (slot) * 4096 + tid * 8;                               \
    async_cp16(ks0, kd);                                                  \
    async_cp16(ks0 + 32 * HEAD_D, kd + 2048);                             \
    async_cp16(vs0, vd);                                                  \
    async_cp16(vs0 + (size_t)32 * T_SEQ, vd + 2048);                      \
  } while (0)

  STAGE_KV(0, 0);  // tile 0 DMA overlaps Q staging below

  // ---- stage Q tile (already exp2-prescaled by projection) ----
  {
    const int row = tid >> 1;
    const int c0 = (tid & 1) * 32;
    const u16* gp = Qg + ((size_t)bh * T_SEQ + q0 + row) * HEAD_D + c0;
#pragma unroll
    for (int g = 0; g < 4; g++) {
      int4 v = *(const int4*)(gp + g * 8);
      int pg = ((c0 >> 3) + g) ^ (row & 7);
      *(int4*)(QPs + row * 64 + pg * 8) = v;
    }
  }
  __syncthreads();  // drains vmcnt+lgkm: Q written, K/V tile 0 landed

  bfv8 qb[2][2];
#pragma unroll
  for (int nt = 0; nt < 2; nt++)
#pragma unroll
    for (int ks = 0; ks < 2; ks++) {
      int q = wave * 32 + nt * 16 + l15;
      int pg = (ks * 4 + quad) ^ (q & 7);
      qb[nt][ks] = *(const bfv8*)(QPs + q * 64 + pg * 8);
    }

  float l_i[2] = {0.f, 0.f};
  f32x4 ao[4][2];
#pragma unroll
  for (int mt = 0; mt < 4; mt++)
#pragma unroll
    for (int nt = 0; nt < 2; nt++) ao[mt][nt] = {0.f, 0.f, 0.f, 0.f};

  const int ktmax = 2 * qt + 1;
  for (int kt = 0; kt <= ktmax; kt++) {
    if (kt < ktmax) STAGE_KV((kt + 1) & 1, kt + 1);  // in flight under compute
    const u16* Ksb = Ks + (kt & 1) * 4096;
    const u16* Vtb = Vt + (kt & 1) * 4096;

    // ---- S^T = K · Q^T ----
    f32x4 as[4][2];
#pragma unroll
    for (int mt = 0; mt < 4; mt++)
#pragma unroll
      for (int nt = 0; nt < 2; nt++) as[mt][nt] = {0.f, 0.f, 0.f, 0.f};
#pragma unroll
    for (int mt = 0; mt < 4; mt++) {
      bfv8 ka[2];
#pragma unroll
      for (int ks = 0; ks < 2; ks++) {
        int key = mt * 16 + l15;
        int pg = (ks * 4 + quad) ^ (key & 7);
        ka[ks] = *(const bfv8*)(Ksb + key * 64 + pg * 8);
      }
#pragma unroll
      for (int nt = 0; nt < 2; nt++)
#pragma unroll
        for (int ks = 0; ks < 2; ks++)
          as[mt][nt] = __builtin_amdgcn_mfma_f32_16x16x32_bf16(
              ka[ks], qb[nt][ks], as[mt][nt], 0, 0, 0);
    }

    // ---- softmax: p = exp2(s) (fixed-max scale cancels in O/l) ----
    const bool diag = (kt >= 2 * qt);
#pragma unroll
    for (int nt = 0; nt < 2; nt++) {
      const int q_l = wave * 32 + nt * 16 + l15;
      const int q_g = q0 + q_l;
      float lacc = 0.f;
#pragma unroll
      for (int mt = 0; mt < 4; mt++) {
        float p[4];
#pragma unroll
        for (int r = 0; r < 4; r++) {
          float s = as[mt][nt][r];
          if (diag) {
            int key_g = kt * 64 + mt * 16 + quad * 4 + r;
            if (key_g > q_g) s = -1e30f;  // exp2 -> 0
          }
          p[r] = fexp2(s);
        }
        lacc += (p[0] + p[1]) + (p[2] + p[3]);
        int pg = (2 * mt + (quad >> 1)) ^ (q_l & 7);
        int2 o;
        o.x = (int)pkbf16(p[0], p[1]);
        o.y = (int)pkbf16(p[2], p[3]);
        *(int2*)(QPs + q_l * 64 + pg * 8 + (quad & 1) * 4) = o;
      }
      l_i[nt] += lacc;
    }

    // ---- O^T += V^T · P ----
    bfv8 pf[2][2];
#pragma unroll
    for (int nt = 0; nt < 2; nt++)
#pragma unroll
      for (int ks = 0; ks < 2; ks++) {
        int q_l = wave * 32 + nt * 16 + l15;
        int pg = (ks * 4 + quad) ^ (q_l & 7);
        pf[nt][ks] = *(const bfv8*)(QPs + q_l * 64 + pg * 8);
      }
#pragma unroll
    for (int mt = 0; mt < 4; mt++) {
      bfv8 va[2];
#pragma unroll
      for (int ks = 0; ks < 2; ks++) {
        int d = mt * 16 + l15;
        int pg = (ks * 4 + quad) ^ (d & 7);
        va[ks] = *(const bfv8*)(Vtb + d * 64 + pg * 8);
      }
#pragma unroll
      for (int nt = 0; nt < 2; nt++)
#pragma unroll
        for (int ks = 0; ks < 2; ks++)
          ao[mt][nt] = __builtin_amdgcn_mfma_f32_16x16x32_bf16(
              va[ks], pf[nt][ks], ao[mt][nt], 0, 0, 0);
    }

    // next tile landed; this tile's LDS reads all retired (consumed by
    // the MFMAs above).  One barrier per k-tile.
    asm volatile("s_waitcnt vmcnt(0)" ::: "memory");
    __builtin_amdgcn_s_barrier();
  }
#undef STAGE_KV

  // ---- final l reduction across quads ----
#pragma unroll
  for (int nt = 0; nt < 2; nt++) {
    l_i[nt] += __shfl_xor(l_i[nt], 16);
    l_i[nt] += __shfl_xor(l_i[nt], 32);
  }

  // ---- epilogue: O^T -> LDS bounce (QPs) -> coalesced Y stores ----
  __syncthreads();
#pragma unroll
  for (int nt = 0; nt < 2; nt++) {
    float inv = 1.0f / l_i[nt];
    int q_l = wave * 32 + nt * 16 + l15;
#pragma unroll
    for (int mt = 0; mt < 4; mt++) {
      int g = mt * 4 + quad;
      int gp = g ^ (q_l & 15);
      int2 o;
      o.x = (int)pkbf16(ao[mt][nt][0] * inv, ao[mt][nt][1] * inv);
      o.y = (int)pkbf16(ao[mt][nt][2] * inv, ao[mt][nt][3] * inv);
      *(int2*)(QPs + q_l * 64 + gp * 4) = o;
    }
  }
  __syncthreads();
#pragma unroll
  for (int rr = 0; rr < 4; rr++) {
    int q   = rr * 32 + (tid >> 3);
    int seg = tid & 7;
    int g0 = (2 * seg) ^ (q & 15), g1 = (2 * seg + 1) ^ (q & 15);
    int2 a  = *(const int2*)(QPs + q * 64 + g0 * 4);
    int2 bv = *(const int2*)(QPs + q * 64 + g1 * 4);
    int4 o; o.x = a.x; o.y = a.y; o.z = bv.x; o.w = bv.y;
    *(int4*)(Yg + ((size_t)b * T_SEQ + q0 + q) * C_DIM + h * HEAD_D + seg * 8) = o;
  }
}

extern "C" void kernel_launch(void* const* d_in, const int* in_sizes, int n_in,
                              void* d_out, int out_size, void* d_ws, size_t ws_size,
                              hipStream_t stream) {
  const float* x  = (const float*)d_in[0];
  const float* Wq = (const float*)d_in[1];
  const float* Wk = (const float*)d_in[2];
  const float* Wv = (const float*)d_in[3];
  const float* Wo = (const float*)d_in[4];
  float* out = (float*)d_out;

  const size_t NE = (size_t)B_SZ * T_SEQ * C_DIM;  // 8388608
  const size_t NW = (size_t)C_DIM * C_DIM;         // 1048576
  u16* xbf = (u16*)d_ws;
  u16* wqb = xbf + NE;   // 4 weight buffers contiguous
  u16* wkb = wqb + NW;
  u16* wvb = wkb + NW;
  u16* wob = wvb + NW;
  u16* qws = wob + NW;
  u16* kws = qws + NE;
  u16* vws = kws + NE;   // V^T layout (B,H,D,T)
  u16* yws = vws + NE;

  // x: 8192 blocks; weights: 4 x 1024 blocks — one dispatch
  cvt_all_kernel<<<8192 + 4096, 256, 0, stream>>>(x, Wq, Wk, Wv, Wo, xbf);

  dim3 g1(T_SEQ * B_SZ / 128, C_DIM / 128, 3);
  gemm_qkv_kernel<<<g1, 256, 0, stream>>>(xbf, wqb, wkb, wvb, qws, kws, vws);

  dim3 g2(B_SZ * N_HEAD, T_SEQ / ATT_Q);
  attn_kernel<<<g2, 256, 0, stream>>>(qws, kws, vws, yws);

  dim3 g3(T_SEQ * B_SZ / 128, C_DIM / 128);
  gemm_out_kernel<<<g3, 256, 0, stream>>>(yws, wob, out);
}